// Round 1
// 1869.980 us; speedup vs baseline: 9.5935x; 9.5935x over previous
//
#include <hip/hip_runtime.h>
#include <stdint.h>
#include <stddef.h>

#define Bb   256
#define Tt   500
#define NIN  128
#define NH   512
#define NOUT 64

typedef __attribute__((ext_vector_type(8))) short  short8;   // 8 bf16 (4 VGPRs)
typedef __attribute__((ext_vector_type(4))) float  float4v;
typedef __attribute__((ext_vector_type(2))) float  float2v;

__device__ __forceinline__ unsigned short f2b(float f) {
    union { float f; unsigned u; } v; v.f = f;
    unsigned u = v.u;
    unsigned r = (u + 0x7FFFu + ((u >> 16) & 1u)) >> 16;  // RNE
    return (unsigned short)r;
}

// load 8 consecutive fp32 (16B-aligned) and convert to a bf16x8 fragment
__device__ __forceinline__ short8 cvt8(const float* __restrict__ p) {
    const float4v a = *(const float4v*)p;
    const float4v b = *(const float4v*)(p + 4);
    short8 r;
    r[0] = (short)f2b(a[0]); r[1] = (short)f2b(a[1]);
    r[2] = (short)f2b(a[2]); r[3] = (short)f2b(a[3]);
    r[4] = (short)f2b(b[0]); r[5] = (short)f2b(b[1]);
    r[6] = (short)f2b(b[2]); r[7] = (short)f2b(b[3]);
    return r;
}

// 16B bf16 fragment via two relaxed agent-scope u64 atomic loads.
// Atomic loads are routed past L1/L2 to the coherence point -> always fresh,
// NO buffer_inv needed (this is the whole point: zero cache-maintenance ops).
__device__ __forceinline__ short8 ld_frag_cp(const unsigned short* p) {
    unsigned long long lo = __hip_atomic_load((const unsigned long long*)p,
                                              __ATOMIC_RELAXED, __HIP_MEMORY_SCOPE_AGENT);
    unsigned long long hi = __hip_atomic_load((const unsigned long long*)(p + 4),
                                              __ATOMIC_RELAXED, __HIP_MEMORY_SCOPE_AGENT);
    union { unsigned long long u[2]; short8 s; } v;
    v.u[0] = lo; v.u[1] = hi;
    return v.s;
}

__global__ void init_flags_kernel(unsigned int* flags) {
    flags[threadIdx.x] = 0u;  // 256 entries = 16 groups x 16 slices
}

// Persistent recurrent kernel. 256 wgs x 256 thr.
// wg -> (g = batch group of 16 rows, s = 32-col hidden slice).
// DECODE SWIZZLED vs previous version: g = wg&15, s = wg>>4, so the 16 wgs of
// a sync-group have ids == g (mod 16) -> same XCD under round-robin dispatch
// (performance heuristic only; correctness never depends on placement).
// h exchanged via relaxed agent-scope atomics (coherence-point routed); flag
// release ordered by per-wave s_waitcnt vmcnt(0) + barrier. No __threadfence,
// no acquire fences -> no per-step L2-wide buffer_inv/buffer_wbl2 storms.
__global__ void __launch_bounds__(256) rnn_persist(
    const float* __restrict__ x,      // [B][T][NIN]
    const float* __restrict__ h0,     // [B][NH]
    const float* __restrict__ Wih,    // [NH][NIN]
    const float* __restrict__ Whh,    // [NH][NH]
    const float* __restrict__ bih,    // [NH]
    const float* __restrict__ bhh,    // [NH]
    const float* __restrict__ alpha,  // [NH]
    float* __restrict__ out,          // full output buffer
    unsigned short* __restrict__ Hx,  // ws: [2][B][NH] bf16
    unsigned int* __restrict__ flags) // ws: [16 groups][16 slices]
{
    const int wg  = blockIdx.x;
    const int g   = wg & 15;   // batch group   (swizzle: same XCD per group)
    const int s   = wg >> 4;   // hidden slice
    const int r0  = g << 4;    // first batch row
    const int c0  = s << 5;    // first hidden col
    const int tid = threadIdx.x;
    const int w   = tid >> 6;  // wave 0..3 (K-split)
    const int l   = tid & 63;
    const int l15 = l & 15;
    const int q   = l >> 4;

    // partial-C exchange: [wave][ntile][quad][lane15][reg] fp32
    __shared__ float Cred[4 * 2 * 4 * 16 * 4];

    // ---- stationary weight fragments (loaded once, fp32 -> bf16) ----
    // B-frag layout: B[k][n], n = lane&15, k = quad*8 + j (8 contiguous k)
    short8 fw_hh[2][4], fw_ih[2];
    for (int nt = 0; nt < 2; ++nt) {
        for (int i = 0; i < 4; ++i) {
            const float* p = Whh + (size_t)(c0 + nt * 16 + l15) * NH
                                 + (4 * w + i) * 32 + q * 8;
            fw_hh[nt][i] = cvt8(p);
        }
        fw_ih[nt] = cvt8(Wih + (size_t)(c0 + nt * 16 + l15) * NIN + w * 32 + q * 8);
    }

    // ---- per-thread epilogue state (thread -> (row, 2 cols)) ----
    const int urow = tid >> 4;           // 0..15 batch-local row
    const int ucol = (tid & 15) * 2;     // 0..30 col pair within slice
    const int gb   = r0 + urow;          // global batch row
    float hcur0 = h0[(size_t)gb * NH + c0 + ucol];
    float hcur1 = h0[(size_t)gb * NH + c0 + ucol + 1];
    const float bias0 = bih[c0 + ucol]     + bhh[c0 + ucol];
    const float bias1 = bih[c0 + ucol + 1] + bhh[c0 + ucol + 1];
    const float al0 = alpha[c0 + ucol], al1 = alpha[c0 + ucol + 1];

    float* hid_out   = out;                                        // [B][T][NH]
    float* final_out = out + (size_t)Bb * Tt * NH + (size_t)Bb * Tt * NOUT; // [B][NH]

    unsigned int* gflags = flags + g * 16;

    for (int t = 0; t < Tt; ++t) {
        // prefetch x fragment for this step (independent of peers -> hides
        // its L2/L3 latency under the flag wait)
        const short8 ax = cvt8(x + ((size_t)(r0 + l15) * Tt + t) * NIN + w * 32 + q * 8);

        if (t > 0) {
            if (tid < 16) {  // wave-0 lanes 0..15 each spin on one peer flag
                const unsigned int* fp = gflags + tid;
                // RELAXED polls: no per-iteration buffer_inv. Visibility of the
                // peer's Hx data comes from the data loads themselves being
                // coherence-point atomics, not from an acquire fence.
                while (__hip_atomic_load(fp, __ATOMIC_RELAXED,
                                         __HIP_MEMORY_SCOPE_AGENT) < (unsigned)t)
                    __builtin_amdgcn_s_sleep(1);
            }
            __syncthreads();
        }

        // ---- A fragments: A[m][k], m = lane&15 (batch row), k contiguous ----
        short8 ah[4];
        if (t == 0) {
            for (int i = 0; i < 4; ++i)
                ah[i] = cvt8(h0 + (size_t)(r0 + l15) * NH + (4 * w + i) * 32 + q * 8);
        } else {
            const unsigned short* hb = Hx + (size_t)((t - 1) & 1) * Bb * NH
                                          + (size_t)(r0 + l15) * NH;
            for (int i = 0; i < 4; ++i)
                ah[i] = ld_frag_cp(hb + (4 * w + i) * 32 + q * 8);
        }

        // ---- MFMA: each wave covers K quarter (128 of Whh + 32 of Wih) ----
        for (int nt = 0; nt < 2; ++nt) {
            float4v acc = {0.f, 0.f, 0.f, 0.f};
            for (int i = 0; i < 4; ++i)
                acc = __builtin_amdgcn_mfma_f32_16x16x32_bf16(ah[i], fw_hh[nt][i], acc, 0, 0, 0);
            acc = __builtin_amdgcn_mfma_f32_16x16x32_bf16(ax, fw_ih[nt], acc, 0, 0, 0);
            // D layout: m = quad*4 + reg, n = lane&15
            *(float4v*)&Cred[(((w * 2 + nt) * 4 + q) * 16 + l15) * 4] = acc;
        }
        __syncthreads();

        // ---- cross-wave K reduction + fused epilogue ----
        const int nt0 = ucol >> 4,       n0 = ucol & 15;
        const int nt1 = (ucol + 1) >> 4, n1 = (ucol + 1) & 15;
        const int qq = urow >> 2, rr = urow & 3;
        float s0 = 0.f, s1 = 0.f;
        for (int ww = 0; ww < 4; ++ww) {
            s0 += Cred[(((ww * 2 + nt0) * 4 + qq) * 16 + n0) * 4 + rr];
            s1 += Cred[(((ww * 2 + nt1) * 4 + qq) * 16 + n1) * 4 + rr];
        }
        float cand0 = s0 + bias0; cand0 = cand0 > 0.f ? cand0 : 0.f;
        float cand1 = s1 + bias1; cand1 = cand1 > 0.f ? cand1 : 0.f;
        hcur0 = (1.f - al0) * hcur0 + al0 * cand0;
        hcur1 = (1.f - al1) * hcur1 + al1 * cand1;

        // bf16 h to exchange buffer: relaxed agent atomic store (packed 4B).
        // Routed to the coherence point -> peer atomic loads see it without
        // any writeback fence.
        const unsigned int packed = (unsigned)f2b(hcur0) | ((unsigned)f2b(hcur1) << 16);
        __hip_atomic_store(
            (unsigned int*)(Hx + (size_t)(t & 1) * Bb * NH + (size_t)gb * NH + c0 + ucol),
            packed, __ATOMIC_RELAXED, __HIP_MEMORY_SCOPE_AGENT);

        // Completion ordering: per-wave vmcnt(0) guarantees the Hx atomic
        // stores have completed at the coherence point; the barrier makes all
        // four waves' drains happen-before tid0's flag store.
        asm volatile("s_waitcnt vmcnt(0)" ::: "memory");
        __syncthreads();
        if (tid == 0)
            __hip_atomic_store(gflags + s, (unsigned)(t + 1),
                               __ATOMIC_RELAXED, __HIP_MEMORY_SCOPE_AGENT);

        // fp32 hidden_seq store AFTER the flag release: output-only data,
        // off the inter-wg critical path (drained by next step's vmcnt(0)).
        const float2v hv = {hcur0, hcur1};
        *(float2v*)(hid_out + ((size_t)gb * Tt + t) * NH + c0 + ucol) = hv;
        if (t == Tt - 1)
            *(float2v*)(final_out + (size_t)gb * NH + c0 + ucol) = hv;
    }
}

// output_seq = hidden_seq @ W_out^T + b_out. rows = b*T+t (same for in/out).
// 2000 wgs x 256 thr; wave -> 16-col tile, 4 row-subtiles of 16, K=512.
__global__ void __launch_bounds__(256) out_proj(
    const float* __restrict__ hid,   // [B*T][NH] (= d_out base)
    const float* __restrict__ Wout,  // [NOUT][NH]
    const float* __restrict__ bout,  // [NOUT]
    float* __restrict__ outp)        // [B*T][NOUT]
{
    const int tid = threadIdx.x;
    const int w = tid >> 6, l = tid & 63, l15 = l & 15, q = l >> 4;
    const size_t rid0 = (size_t)blockIdx.x * 64;

    short8 fb[16];
    for (int kc = 0; kc < 16; ++kc)
        fb[kc] = cvt8(Wout + (size_t)(w * 16 + l15) * NH + kc * 32 + q * 8);
    const float bv = bout[w * 16 + l15];

    for (int rs = 0; rs < 4; ++rs) {
        float4v acc = {bv, bv, bv, bv};
        const float* ap = hid + (rid0 + rs * 16 + l15) * NH + q * 8;
        for (int kc = 0; kc < 16; ++kc)
            acc = __builtin_amdgcn_mfma_f32_16x16x32_bf16(cvt8(ap + kc * 32), fb[kc], acc, 0, 0, 0);
        for (int r = 0; r < 4; ++r) {
            size_t rid = rid0 + rs * 16 + q * 4 + r;   // m = quad*4 + reg
            outp[rid * NOUT + w * 16 + l15] = acc[r];
        }
    }
}

extern "C" void kernel_launch(void* const* d_in, const int* in_sizes, int n_in,
                              void* d_out, int out_size, void* d_ws, size_t ws_size,
                              hipStream_t stream) {
    (void)in_sizes; (void)n_in; (void)out_size; (void)ws_size;
    const float* x     = (const float*)d_in[0];
    const float* h0    = (const float*)d_in[1];
    const float* Wih   = (const float*)d_in[2];
    const float* Whh   = (const float*)d_in[3];
    const float* bih   = (const float*)d_in[4];
    const float* bhh   = (const float*)d_in[5];
    const float* Wout  = (const float*)d_in[6];
    const float* bout  = (const float*)d_in[7];
    const float* alpha = (const float*)d_in[8];
    float* out = (float*)d_out;

    unsigned short* Hx   = (unsigned short*)d_ws;                       // 512 KB
    unsigned int*  flags = (unsigned int*)((char*)d_ws + (size_t)2 * Bb * NH * 2);

    init_flags_kernel<<<1, 256, 0, stream>>>(flags);

    void* args[] = { (void*)&x, (void*)&h0, (void*)&Wih, (void*)&Whh,
                     (void*)&bih, (void*)&bhh, (void*)&alpha, (void*)&out,
                     (void*)&Hx, (void*)&flags };
    hipLaunchCooperativeKernel((const void*)rnn_persist, dim3(256), dim3(256),
                               args, 0, stream);

    const float* hid = out;
    float* outp = out + (size_t)Bb * Tt * NH;
    out_proj<<<2000, 256, 0, stream>>>(hid, Wout, bout, outp);
}